// Round 2
// 485.972 us; speedup vs baseline: 1.0317x; 1.0317x over previous
//
#include <hip/hip_runtime.h>
#include <hip/hip_bf16.h>

typedef short short8 __attribute__((ext_vector_type(8)));
typedef float floatx4 __attribute__((ext_vector_type(4)));

#define XP 328   // X LDS pitch (bf16): 656 B rows; lane-stride 164 words = 4 mod 32 -> 2-way only
#define HP 168   // H LDS pitch: 336 B rows; lane-stride 84 words = 20 mod 32 -> 2-way only

__device__ __forceinline__ unsigned short f2bf(float f) {
    __hip_bfloat16 h = __float2bfloat16(f);
    return __builtin_bit_cast(unsigned short, h);
}
__device__ __forceinline__ float bf2f(unsigned short s) {
    __hip_bfloat16 h = __builtin_bit_cast(__hip_bfloat16, s);
    return __bfloat162float(h);
}

// Sum across the 16 lanes of a DPP "row" using v_add_f32_dpp (row_ror) — pure VALU,
// replaces __shfl_xor which lowers to ds_bpermute and burns the CU-shared LDS pipe.
__device__ __forceinline__ float dpp_sum16(float v) {
    v += __builtin_bit_cast(float, __builtin_amdgcn_update_dpp(
             0, __builtin_bit_cast(int, v), 0x128, 0xF, 0xF, true));  // row_ror:8
    v += __builtin_bit_cast(float, __builtin_amdgcn_update_dpp(
             0, __builtin_bit_cast(int, v), 0x124, 0xF, 0xF, true));  // row_ror:4
    v += __builtin_bit_cast(float, __builtin_amdgcn_update_dpp(
             0, __builtin_bit_cast(int, v), 0x122, 0xF, 0xF, true));  // row_ror:2
    v += __builtin_bit_cast(float, __builtin_amdgcn_update_dpp(
             0, __builtin_bit_cast(int, v), 0x121, 0xF, 0xF, true));  // row_ror:1
    return v;
}

// Pack Wc = [w1; wt] (320x320) into B-fragment order for mfma_f32_16x16x32_bf16.
// elem j of lane l for (t,kb): n = t*16+(l&15), k = kb*32+(l>>4)*8+j; flat (((t*10+kb)*64+l)*8+j)
__global__ void pack_wc(const float* __restrict__ w1, const float* __restrict__ wt,
                        unsigned short* __restrict__ dst) {
    int i = blockIdx.x * 256 + threadIdx.x;
    if (i >= 320 * 320) return;
    int j = i & 7;
    int lane = (i >> 3) & 63;
    int r = i >> 9;
    int kb = r % 10;
    int t = r / 10;
    int n = t * 16 + (lane & 15);
    int k = kb * 32 + ((lane >> 4) << 3) + j;
    float v = (n < 160) ? w1[n * 320 + k] : wt[(n - 160) * 320 + k];
    dst[i] = f2bf(v);
}

__global__ void pack_w2(const float* __restrict__ w2, unsigned short* __restrict__ dst) {
    int i = blockIdx.x * 256 + threadIdx.x;
    if (i >= 160 * 160) return;
    int j = i & 7;
    int lane = (i >> 3) & 63;
    int r = i >> 9;
    int kb = r % 5;
    int t = r / 5;
    int n = t * 16 + (lane & 15);
    int k = kb * 32 + ((lane >> 4) << 3) + j;
    dst[i] = f2bf(w2[n * 160 + k]);
}

__global__ __launch_bounds__(256, 3) void fused_kernel(
    const float* __restrict__ actors, const float* __restrict__ paths,
    const float* __restrict__ Z_act, const float* __restrict__ Z_pat,
    const int* __restrict__ u,
    const unsigned short* __restrict__ pB1, const unsigned short* __restrict__ pB2,
    const float* __restrict__ g1w, const float* __restrict__ g1b,
    const float* __restrict__ g2w, const float* __restrict__ g2b,
    const float* __restrict__ wh, const float* __restrict__ bh,
    float* __restrict__ out)
{
    // LDS map: [0,41984) lX (64 x XP bf16).  After GEMM1: [0,21504) lH1 (64 x HP bf16),
    // [21504,41984) lHT packed [ch 0..160][rg 0..16] ushort4 (4 rows each), rg XOR-swizzled.
    // Stats at 41984: sSum[128], sSq[128], sStat float2[64].
    __shared__ __align__(16) char smem[43520];
    unsigned short* lX  = (unsigned short*)smem;
    unsigned short* lH1 = (unsigned short*)smem;
    unsigned short* lHT = (unsigned short*)(smem + 21504);
    float*  sSum  = (float*)(smem + 41984);   // [2][64]
    float*  sSq   = sSum + 128;               // [2][64]
    float2* sStat = (float2*)(smem + 41984 + 1024);  // [64] {mu, rstd}

    const int tid  = threadIdx.x;
    const int wave = tid >> 6;
    const int lane = tid & 63;
    const int quad = lane >> 4;
    const int l15  = lane & 15;
    const int row0 = blockIdx.x * 64;

    // ================= staging: phase-split for MLP =================
    // direct space: 64 rows x 40 quads (k 0..159); gather space: 64 x 40 (k 160..319)
    float4 vD[10], vG[10];
    int uv[10];
    #pragma unroll
    for (int i = 0; i < 10; i++) {          // phase A: direct loads + u loads
        int f = i * 256 + tid;
        int r = f / 40, q = f - r * 40;
        const float* src = (q < 32) ? (paths + (size_t)(row0 + r) * 128 + q * 4)
                                    : (Z_pat + (size_t)(row0 + r) * 32 + (q - 32) * 4);
        vD[i] = *(const float4*)src;
        uv[i] = u[row0 + r];
    }
    #pragma unroll
    for (int i = 0; i < 10; i++) {          // phase B: dependent gather loads
        int f = i * 256 + tid;
        int r = f / 40, q = f - r * 40;
        (void)r;
        int un = uv[i];
        const float* src = (q < 32) ? (actors + (size_t)un * 128 + q * 4)
                                    : (Z_act + (size_t)un * 32 + (q - 32) * 4);
        vG[i] = *(const float4*)src;
    }
    #pragma unroll
    for (int i = 0; i < 10; i++) {          // phase C: convert + LDS write
        int f = i * 256 + tid;
        int r = f / 40, q = f - r * 40;
        ushort4 sv;
        sv.x = f2bf(vD[i].x); sv.y = f2bf(vD[i].y); sv.z = f2bf(vD[i].z); sv.w = f2bf(vD[i].w);
        *(ushort4*)(lX + r * XP + q * 4) = sv;
    }
    #pragma unroll
    for (int i = 0; i < 10; i++) {
        int f = i * 256 + tid;
        int r = f / 40, q = f - r * 40;
        ushort4 sv;
        sv.x = f2bf(vG[i].x); sv.y = f2bf(vG[i].y); sv.z = f2bf(vG[i].z); sv.w = f2bf(vG[i].w);
        *(ushort4*)(lX + r * XP + 160 + q * 4) = sv;
    }

    // prefetch GEMM1 B fragments kb=0,1 (independent of LDS) before the barrier
    short8 bA[5], bB[5];
    #pragma unroll
    for (int ti = 0; ti < 5; ti++) {
        int t = wave * 5 + ti;
        bA[ti] = *(const short8*)(pB1 + ((size_t)(t * 10 + 0) * 64 + lane) * 8);
        bB[ti] = *(const short8*)(pB1 + ((size_t)(t * 10 + 1) * 64 + lane) * 8);
    }
    __syncthreads();

    // ================= GEMM1: C[64x320] = X @ [w1;wt]^T, n-split by wave =================
    floatx4 fzero = {0.f, 0.f, 0.f, 0.f};
    floatx4 acc[4][5];
    #pragma unroll
    for (int i = 0; i < 4; i++)
        #pragma unroll
        for (int j = 0; j < 5; j++) acc[i][j] = fzero;

    #pragma unroll
    for (int kb = 0; kb < 10; kb++) {
        short8 a[4];
        #pragma unroll
        for (int mt = 0; mt < 4; mt++)
            a[mt] = *(const short8*)(lX + (mt * 16 + l15) * XP + kb * 32 + quad * 8);
        short8 bN[5];
        if (kb + 2 < 10) {
            #pragma unroll
            for (int ti = 0; ti < 5; ti++) {
                int t = wave * 5 + ti;
                bN[ti] = *(const short8*)(pB1 + ((size_t)(t * 10 + kb + 2) * 64 + lane) * 8);
            }
        }
        #pragma unroll
        for (int ti = 0; ti < 5; ti++) {
            #pragma unroll
            for (int mt = 0; mt < 4; mt++)
                acc[mt][ti] = __builtin_amdgcn_mfma_f32_16x16x32_bf16(a[mt], bA[ti], acc[mt][ti], 0, 0, 0);
        }
        #pragma unroll
        for (int ti = 0; ti < 5; ti++) { bA[ti] = bB[ti]; bB[ti] = bN[ti]; }
    }
    __syncthreads();   // lX dead; safe to write lH1/lHT

    // ================= split: waves 2,3 write ht (packed b64); waves 0,1 GN1 stats (DPP) ==========
    if (wave >= 2) {
        int wn2 = wave - 2;
        #pragma unroll
        for (int mtp = 0; mtp < 4; mtp++)
            #pragma unroll
            for (int ti = 0; ti < 5; ti++) {
                ushort4 sv;
                sv.x = f2bf(acc[mtp][ti][0]);
                sv.y = f2bf(acc[mtp][ti][1]);
                sv.z = f2bf(acc[mtp][ti][2]);
                sv.w = f2bf(acc[mtp][ti][3]);
                int ch = wn2 * 80 + ti * 16 + l15;          // ht channel
                int rg = (mtp * 4 + quad) ^ l15;            // row-group, XOR-swizzled for banks
                *(ushort4*)(lHT + ch * 64 + rg * 4) = sv;   // 4 rows (r=0..3) packed
            }
    } else {
        float s[16], q2[16];
        #pragma unroll
        for (int mt = 0; mt < 4; mt++)
            #pragma unroll
            for (int r = 0; r < 4; r++) {
                float sv = 0.f, qv = 0.f;
                #pragma unroll
                for (int ti = 0; ti < 5; ti++) {
                    float v = acc[mt][ti][r];
                    sv += v; qv += v * v;
                }
                s[mt * 4 + r] = sv; q2[mt * 4 + r] = qv;
            }
        #pragma unroll
        for (int k = 0; k < 16; k++) {
            s[k]  = dpp_sum16(s[k]);
            q2[k] = dpp_sum16(q2[k]);
        }
        if (l15 == 0) {
            #pragma unroll
            for (int mt = 0; mt < 4; mt++)
                #pragma unroll
                for (int r = 0; r < 4; r++) {
                    int m = mt * 16 + quad * 4 + r;
                    sSum[wave * 64 + m] = s[mt * 4 + r];
                    sSq[wave * 64 + m]  = q2[mt * 4 + r];
                }
        }
    }
    __syncthreads();

    if (tid < 64) {
        float ts = sSum[tid] + sSum[64 + tid];
        float tq = sSq[tid] + sSq[64 + tid];
        float mu = ts * (1.f / 160.f);
        float var = tq * (1.f / 160.f) - mu * mu;
        float2 st; st.x = mu; st.y = rsqrtf(var + 1e-5f);
        sStat[tid] = st;
    }
    __syncthreads();

    // ================= GN1 apply + ReLU + write h1 (waves 0,1) =================
    if (wave < 2) {
        float gw[5], gb[5];
        #pragma unroll
        for (int ti = 0; ti < 5; ti++) {
            int n = wave * 80 + ti * 16 + l15;
            gw[ti] = g1w[n]; gb[ti] = g1b[n];
        }
        #pragma unroll
        for (int mt = 0; mt < 4; mt++)
            #pragma unroll
            for (int r = 0; r < 4; r++) {
                int m = mt * 16 + quad * 4 + r;
                float2 st = sStat[m];
                #pragma unroll
                for (int ti = 0; ti < 5; ti++) {
                    float v = (acc[mt][ti][r] - st.x) * st.y * gw[ti] + gb[ti];
                    v = fmaxf(v, 0.f);
                    lH1[m * HP + wave * 80 + ti * 16 + l15] = f2bf(v);
                }
            }
    }

    // prefetch GEMM2 B fragments kb=0,1
    const int wm = wave & 1, wn = wave >> 1;
    short8 b2A[5], b2B[5];
    #pragma unroll
    for (int ti = 0; ti < 5; ti++) {
        int t = wn * 5 + ti;
        b2A[ti] = *(const short8*)(pB2 + ((size_t)(t * 5 + 0) * 64 + lane) * 8);
        b2B[ti] = *(const short8*)(pB2 + ((size_t)(t * 5 + 1) * 64 + lane) * 8);
    }
    __syncthreads();

    // ================= GEMM2: h2[64x160] = h1 @ w2^T; (wm rows-half, wn cols-half) =================
    floatx4 acc2[2][5];
    #pragma unroll
    for (int i = 0; i < 2; i++)
        #pragma unroll
        for (int j = 0; j < 5; j++) acc2[i][j] = fzero;

    #pragma unroll
    for (int kb = 0; kb < 5; kb++) {
        short8 a[2];
        #pragma unroll
        for (int mt = 0; mt < 2; mt++)
            a[mt] = *(const short8*)(lH1 + (wm * 32 + mt * 16 + l15) * HP + kb * 32 + quad * 8);
        short8 bN[5];
        if (kb + 2 < 5) {
            #pragma unroll
            for (int ti = 0; ti < 5; ti++) {
                int t = wn * 5 + ti;
                bN[ti] = *(const short8*)(pB2 + ((size_t)(t * 5 + kb + 2) * 64 + lane) * 8);
            }
        }
        #pragma unroll
        for (int ti = 0; ti < 5; ti++) {
            #pragma unroll
            for (int mt = 0; mt < 2; mt++)
                acc2[mt][ti] = __builtin_amdgcn_mfma_f32_16x16x32_bf16(a[mt], b2A[ti], acc2[mt][ti], 0, 0, 0);
        }
        #pragma unroll
        for (int ti = 0; ti < 5; ti++) { b2A[ti] = b2B[ti]; b2B[ti] = bN[ti]; }
    }

    // ================= GN2 stats (in-register, DPP reduce) =================
    {
        float s[8], q2[8];
        #pragma unroll
        for (int mt = 0; mt < 2; mt++)
            #pragma unroll
            for (int r = 0; r < 4; r++) {
                float sv = 0.f, qv = 0.f;
                #pragma unroll
                for (int ti = 0; ti < 5; ti++) {
                    float v = acc2[mt][ti][r];
                    sv += v; qv += v * v;
                }
                s[mt * 4 + r] = sv; q2[mt * 4 + r] = qv;
            }
        #pragma unroll
        for (int k = 0; k < 8; k++) {
            s[k]  = dpp_sum16(s[k]);
            q2[k] = dpp_sum16(q2[k]);
        }
        if (l15 == 0) {
            #pragma unroll
            for (int mt = 0; mt < 2; mt++)
                #pragma unroll
                for (int r = 0; r < 4; r++) {
                    int m = wm * 32 + mt * 16 + quad * 4 + r;
                    sSum[wn * 64 + m] = s[mt * 4 + r];
                    sSq[wn * 64 + m]  = q2[mt * 4 + r];
                }
        }
    }
    __syncthreads();

    if (tid < 64) {
        float ts = sSum[tid] + sSum[64 + tid];
        float tq = sSq[tid] + sSq[64 + tid];
        float mu = ts * (1.f / 160.f);
        float var = tq * (1.f / 160.f) - mu * mu;
        float2 st; st.x = mu; st.y = rsqrtf(var + 1e-5f);
        sStat[tid] = st;
    }
    __syncthreads();

    // ================= GN2 apply + skip(ht, packed b64) + ReLU + head dot =================
    {
        float g2wv[5], g2bv[5], whv[5];
        #pragma unroll
        for (int ti = 0; ti < 5; ti++) {
            int n = wn * 80 + ti * 16 + l15;
            g2wv[ti] = g2w[n]; g2bv[ti] = g2b[n]; whv[ti] = wh[n];
        }
        float2 st2[2][4];
        #pragma unroll
        for (int mt = 0; mt < 2; mt++)
            #pragma unroll
            for (int r = 0; r < 4; r++)
                st2[mt][r] = sStat[wm * 32 + mt * 16 + quad * 4 + r];

        float dp[8];
        #pragma unroll
        for (int k = 0; k < 8; k++) dp[k] = 0.f;

        #pragma unroll
        for (int mt = 0; mt < 2; mt++)
            #pragma unroll
            for (int ti = 0; ti < 5; ti++) {
                int ch = wn * 80 + ti * 16 + l15;
                int rg = ((wm * 2 + mt) * 4 + quad) ^ l15;
                ushort4 hv = *(const ushort4*)(lHT + ch * 64 + rg * 4);
                float hvf[4];
                hvf[0] = bf2f(hv.x); hvf[1] = bf2f(hv.y);
                hvf[2] = bf2f(hv.z); hvf[3] = bf2f(hv.w);
                #pragma unroll
                for (int r = 0; r < 4; r++) {
                    float v = (acc2[mt][ti][r] - st2[mt][r].x) * st2[mt][r].y * g2wv[ti] + g2bv[ti];
                    v += hvf[r];
                    v = fmaxf(v, 0.f);
                    dp[mt * 4 + r] += v * whv[ti];
                }
            }
        #pragma unroll
        for (int k = 0; k < 8; k++) dp[k] = dpp_sum16(dp[k]);
        // No barrier needed here: dp writes touch only sSum, which no wave reads
        // between the mu-barrier above and the final barrier below (sStat/lHT are disjoint).
        if (l15 == 0) {
            #pragma unroll
            for (int mt = 0; mt < 2; mt++)
                #pragma unroll
                for (int r = 0; r < 4; r++) {
                    int m = wm * 32 + mt * 16 + quad * 4 + r;
                    sSum[wn * 64 + m] = dp[mt * 4 + r];
                }
        }
    }
    __syncthreads();
    if (tid < 64) out[row0 + tid] = sSum[tid] + sSum[64 + tid] + bh[0];
}

extern "C" void kernel_launch(void* const* d_in, const int* in_sizes, int n_in,
                              void* d_out, int out_size, void* d_ws, size_t ws_size,
                              hipStream_t stream) {
    const float* actors = (const float*)d_in[0];
    const float* paths  = (const float*)d_in[1];
    const float* Z_act  = (const float*)d_in[2];
    const float* Z_pat  = (const float*)d_in[3];
    const int*   u      = (const int*)d_in[4];
    const float* w1     = (const float*)d_in[5];
    const float* w2     = (const float*)d_in[6];
    const float* wt     = (const float*)d_in[7];
    const float* g1w    = (const float*)d_in[8];
    const float* g1b    = (const float*)d_in[9];
    const float* g2w    = (const float*)d_in[10];
    const float* g2b    = (const float*)d_in[11];
    const float* wh     = (const float*)d_in[12];
    const float* bh     = (const float*)d_in[13];
    float* out = (float*)d_out;

    unsigned short* pB1 = (unsigned short*)d_ws;
    unsigned short* pB2 = pB1 + 320 * 320;

    hipLaunchKernelGGL(pack_wc, dim3(400), dim3(256), 0, stream, w1, wt, pB1);
    hipLaunchKernelGGL(pack_w2, dim3(100), dim3(256), 0, stream, w2, pB2);
    hipLaunchKernelGGL(fused_kernel, dim3(400000 / 64), dim3(256), 0, stream,
                       actors, paths, Z_act, Z_pat, u, pB1, pB2,
                       g1w, g1b, g2w, g2b, wh, bh, out);
}